// Round 11
// baseline (182.336 us; speedup 1.0000x reference)
//
#include <hip/hip_runtime.h>

#define T 200
#define E 64
#define TPAD 256
#define ROW 72
#define BDIM 256

typedef __bf16 bf16_t;
typedef __bf16 bf16x8 __attribute__((ext_vector_type(8)));
typedef float f32x4 __attribute__((ext_vector_type(4)));

// ---- merged pre-pass: blocks 0..15 fold w1; blocks 16.. convert emb ----
__global__ __launch_bounds__(256) void pre_cvt(const float* __restrict__ embf,
                                               bf16_t* __restrict__ emb16, int n8,
                                               const float* __restrict__ w1,
                                               float* __restrict__ Ap,
                                               float* __restrict__ Ctf,
                                               float* __restrict__ Dtf) {
    const int bid = blockIdx.x;
    if (bid < 16) {
        const int idx = bid * 256 + threadIdx.x;      // 0..4095
        const int e = idx >> 6, j = idx & 63;
        const float a = w1[e * 64 + j];
        const float b = w1[(64 + e) * 64 + j];
        const float c = w1[(128 + e) * 64 + j];
        const float d = w1[(192 + e) * 64 + j];
        Ap[e * 64 + j]  = a + c;
        Ctf[j * 64 + e] = b - c;
        Dtf[j * 64 + e] = d;
        return;
    }
    const int i = (bid - 16) * 256 + threadIdx.x;
    if (i >= n8) return;
    const float4* s = (const float4*)embf + (size_t)i * 2;
    const float4 a = s[0], b = s[1];
    union { bf16_t h[8]; uint4 v; } u;
    u.h[0] = (bf16_t)a.x; u.h[1] = (bf16_t)a.y; u.h[2] = (bf16_t)a.z; u.h[3] = (bf16_t)a.w;
    u.h[4] = (bf16_t)b.x; u.h[5] = (bf16_t)b.y; u.h[6] = (bf16_t)b.z; u.h[7] = (bf16_t)b.w;
    ((uint4*)emb16)[i] = u.v;
}

// ===== R11: one wave per batch, ONE WAVE PER BLOCK (64 threads) =====
// R10 structure frozen (zero __syncthreads, K in MFMA A-fragments in regs,
// M^T per-lane in regs). Changes: 64-thread blocks kill intra-block wave
// coupling (dispatch/drain in 1-wave quanta); serial fma chains split 4-way
// (u-loop, MLP 128->64, MLP 64->128) to cut dependent-latency.
__global__ __launch_bounds__(64, 4) void din_wave(
    const int* __restrict__ query,
    const int* __restrict__ keys,
    const bf16_t* __restrict__ emb16,
    const float* __restrict__ Ap,
    const float* __restrict__ Ctf,
    const float* __restrict__ Dtf,
    const float* __restrict__ b1,
    const float* __restrict__ w2,
    const float* __restrict__ b2,
    const float* __restrict__ dw1,
    const float* __restrict__ db1,
    const float* __restrict__ dw2,
    const float* __restrict__ db2,
    const float* __restrict__ ow,
    const float* __restrict__ ob,
    float* __restrict__ out,
    const int nB)
{
    __shared__ __align__(16) char smem[1664];
    const int lane = threadIdx.x;
    const int n    = lane & 15;
    const int quad = lane >> 4;
    const int b    = blockIdx.x;
    if (b >= nB) return;                               // wave-uniform; no barriers

    float* sWgt = (float*)smem;                        // 208 f32 scores/weights
    float* sInt = (float*)(smem + 832);                // 64 f32 interest
    float* sD1  = (float*)(smem + 1088);               // 128 f32 mlp hidden

    // ---- q fragments (bf16, same rounding as before) ----
    const int qi = query[b];
    const bf16x8 q0 = *(const bf16x8*)(emb16 + (size_t)qi * E + quad * 8);
    const bf16x8 q1 = *(const bf16x8*)(emb16 + (size_t)qi * E + 32 + quad * 8);

    // ---- keys for this lane's GEMM rows: t = mt*16 + n (clamped to row 0) ----
    int kidx[13];
    #pragma unroll
    for (int mt = 0; mt < 13; ++mt) {
        const int t = mt * 16 + n;
        kidx[mt] = (t < T) ? keys[b * T + t] : 0;
    }
    // ---- gather A-fragments directly into registers ----
    bf16x8 a0[13], a1[13];
    #pragma unroll
    for (int mt = 0; mt < 13; ++mt) {
        const bf16_t* rp = emb16 + (size_t)kidx[mt] * E;
        a0[mt] = *(const bf16x8*)(rp + quad * 8);
        a1[mt] = *(const bf16x8*)(rp + 32 + quad * 8);
    }

    // ---- u[lane] = sum_e q[e] * Ap[e][lane]  (4 indep chains) ----
    float ua = 0.f, ub = 0.f, uc = 0.f, ud = 0.f;
    #pragma unroll
    for (int e = 0; e < 64; e += 4) {
        ua = fmaf((float)emb16[(size_t)qi * E + e],     Ap[e * 64 + lane],       ua);
        ub = fmaf((float)emb16[(size_t)qi * E + e + 1], Ap[(e + 1) * 64 + lane], ub);
        uc = fmaf((float)emb16[(size_t)qi * E + e + 2], Ap[(e + 2) * 64 + lane], uc);
        ud = fmaf((float)emb16[(size_t)qi * E + e + 3], Ap[(e + 3) * 64 + lane], ud);
    }
    const float u = (ua + ub) + (uc + ud);

    float uv[4], w2v[4];
    #pragma unroll
    for (int nt = 0; nt < 4; ++nt) {
        const int jj = nt * 16 + n;
        uv[nt]  = b1[jj] + __shfl(u, jj);
        w2v[nt] = w2[jj];
    }

    // ---- build B-fragments (M^T) per-lane in registers ----
    bf16x8 bF[4][2];
    #pragma unroll
    for (int nt = 0; nt < 4; ++nt) {
        const int jj = nt * 16 + n;
        const float* cb = Ctf + jj * 64;
        const float* db = Dtf + jj * 64;
        union { bf16_t h[8]; bf16x8 v; } u0, u1;
        #pragma unroll
        for (int x = 0; x < 8; ++x) {
            u0.h[x] = (bf16_t)fmaf((float)q0[x], db[quad * 8 + x],      cb[quad * 8 + x]);
            u1.h[x] = (bf16_t)fmaf((float)q1[x], db[32 + quad * 8 + x], cb[32 + quad * 8 + x]);
        }
        bF[nt][0] = u0.v;
        bF[nt][1] = u1.v;
    }

    // ---- score GEMM (104 MFMA) + 16-lane reduce -> wave-local LDS ----
    #pragma unroll
    for (int mt = 0; mt < 13; ++mt) {
        float s0 = 0.f, s1 = 0.f, s2 = 0.f, s3 = 0.f;
        #pragma unroll
        for (int nt = 0; nt < 4; ++nt) {
            f32x4 acc = { uv[nt], uv[nt], uv[nt], uv[nt] };
            acc = __builtin_amdgcn_mfma_f32_16x16x32_bf16(a0[mt], bF[nt][0], acc, 0, 0, 0);
            acc = __builtin_amdgcn_mfma_f32_16x16x32_bf16(a1[mt], bF[nt][1], acc, 0, 0, 0);
            s0 = fmaf(fmaxf(acc[0], 0.f), w2v[nt], s0);
            s1 = fmaf(fmaxf(acc[1], 0.f), w2v[nt], s1);
            s2 = fmaf(fmaxf(acc[2], 0.f), w2v[nt], s2);
            s3 = fmaf(fmaxf(acc[3], 0.f), w2v[nt], s3);
        }
        #pragma unroll
        for (int off = 1; off < 16; off <<= 1) {
            s0 += __shfl_xor(s0, off);
            s1 += __shfl_xor(s1, off);
            s2 += __shfl_xor(s2, off);
            s3 += __shfl_xor(s3, off);
        }
        if (n == 0) {
            const int base = mt * 16 + quad * 4;
            sWgt[base + 0] = s0;
            sWgt[base + 1] = s1;
            sWgt[base + 2] = s2;
            sWgt[base + 3] = s3;
        }
    }
    asm volatile("s_waitcnt lgkmcnt(0)" ::: "memory");
    __builtin_amdgcn_sched_barrier(0);

    // ---- wave softmax, normalization folded ----
    {
        const float b2v = b2[0];
        const float x0 = sWgt[lane] + b2v;
        const float x1 = sWgt[64 + lane] + b2v;
        const float x2 = sWgt[128 + lane] + b2v;
        const float x3 = (lane < 8) ? (sWgt[192 + lane] + b2v) : -1e30f;
        float m = fmaxf(fmaxf(x0, x1), fmaxf(x2, x3));
        #pragma unroll
        for (int off = 32; off > 0; off >>= 1) m = fmaxf(m, __shfl_xor(m, off));
        const float p0 = __expf(x0 - m);
        const float p1 = __expf(x1 - m);
        const float p2 = __expf(x2 - m);
        const float p3 = (lane < 8) ? __expf(x3 - m) : 0.f;
        float s = ((p0 + p1) + (p2 + p3));
        #pragma unroll
        for (int off = 32; off > 0; off >>= 1) s += __shfl_xor(s, off);
        const float inv = 1.f / s;
        sWgt[lane]       = p0 * inv;
        sWgt[64 + lane]  = p1 * inv;
        sWgt[128 + lane] = p2 * inv;
        if (lane < 8) sWgt[192 + lane] = p3 * inv;
    }
    asm volatile("s_waitcnt lgkmcnt(0)" ::: "memory");
    __builtin_amdgcn_sched_barrier(0);

    // ---- interest from the SAME register fragments ----
    {
        float pa[8], pb[8];
        #pragma unroll
        for (int x = 0; x < 8; ++x) { pa[x] = 0.f; pb[x] = 0.f; }
        #pragma unroll
        for (int mt = 0; mt < 13; ++mt) {
            const int t = mt * 16 + n;
            const float wt = (t < T) ? sWgt[t] : 0.f;
            #pragma unroll
            for (int x = 0; x < 8; ++x) {
                pa[x] = fmaf(wt, (float)a0[mt][x], pa[x]);
                pb[x] = fmaf(wt, (float)a1[mt][x], pb[x]);
            }
        }
        #pragma unroll
        for (int x = 0; x < 8; ++x) {
            #pragma unroll
            for (int off = 1; off < 16; off <<= 1) {
                pa[x] += __shfl_xor(pa[x], off);
                pb[x] += __shfl_xor(pb[x], off);
            }
        }
        if (n == 0) {
            #pragma unroll
            for (int x = 0; x < 8; ++x) {
                sInt[quad * 8 + x]      = pa[x];
                sInt[32 + quad * 8 + x] = pb[x];
            }
        }
    }
    asm volatile("s_waitcnt lgkmcnt(0)" ::: "memory");
    __builtin_amdgcn_sched_barrier(0);

    // ---- deep MLP 64 -> 128 (2 outputs/lane, 2 chains each) ----
    {
        float d1a0 = db1[lane], d1a1 = 0.f;
        float d1b0 = db1[64 + lane], d1b1 = 0.f;
        #pragma unroll
        for (int e = 0; e < 64; e += 2) {
            const float ie0 = sInt[e], ie1 = sInt[e + 1];
            d1a0 = fmaf(ie0, dw1[e * 128 + lane], d1a0);
            d1a1 = fmaf(ie1, dw1[(e + 1) * 128 + lane], d1a1);
            d1b0 = fmaf(ie0, dw1[e * 128 + 64 + lane], d1b0);
            d1b1 = fmaf(ie1, dw1[(e + 1) * 128 + 64 + lane], d1b1);
        }
        sD1[lane]      = fmaxf(d1a0 + d1a1, 0.f);
        sD1[64 + lane] = fmaxf(d1b0 + d1b1, 0.f);
    }
    asm volatile("s_waitcnt lgkmcnt(0)" ::: "memory");
    __builtin_amdgcn_sched_barrier(0);

    // ---- 128 -> 64 -> 1 (4 chains) ----
    {
        float o0 = db2[lane], o1 = 0.f, o2 = 0.f, o3 = 0.f;
        #pragma unroll
        for (int i = 0; i < 128; i += 4) {
            o0 = fmaf(sD1[i],     dw2[i * 64 + lane],       o0);
            o1 = fmaf(sD1[i + 1], dw2[(i + 1) * 64 + lane], o1);
            o2 = fmaf(sD1[i + 2], dw2[(i + 2) * 64 + lane], o2);
            o3 = fmaf(sD1[i + 3], dw2[(i + 3) * 64 + lane], o3);
        }
        float v = fmaxf((o0 + o1) + (o2 + o3), 0.f) * ow[lane];
        #pragma unroll
        for (int off = 32; off > 0; off >>= 1) v += __shfl_xor(v, off);
        if (lane == 0) out[b] = 1.f / (1.f + __expf(-(v + ob[0])));
    }
}

// ============ fallback: verified kernel (ws too small; fp32 path) ============
__global__ __launch_bounds__(BDIM, 3) void din_kernel(
    const int* __restrict__ query,
    const int* __restrict__ keys,
    const float* __restrict__ embf,
    const bf16_t* __restrict__ emb16,
    const int use16,
    const float* __restrict__ w1,
    const float* __restrict__ b1,
    const float* __restrict__ w2,
    const float* __restrict__ b2,
    const float* __restrict__ dw1,
    const float* __restrict__ db1,
    const float* __restrict__ dw2,
    const float* __restrict__ db2,
    const float* __restrict__ ow,
    const float* __restrict__ ob,
    float* __restrict__ out)
{
    __shared__ __align__(16) char sRaw[TPAD * ROW * 2];
    __shared__ __align__(16) bf16_t sMt[64 * ROW];
    __shared__ float sU[64];
    __shared__ float sUP[256];
    __shared__ float sW2f[64];
    __shared__ float sWgt[256];
    __shared__ float sQf[64];
    __shared__ __align__(16) char sQtmp[128];
    __shared__ float sRed[8];
    __shared__ float sInt[64];
    __shared__ float sD1[128];
    __shared__ float sD2[64];

    const int tid  = threadIdx.x;
    const int lane = tid & 63;
    const int wid  = tid >> 6;
    const int b    = blockIdx.x;
    const float b2v = b2[0];

    uint4 kr[8];
    if (tid < T) {
        const int ki = keys[b * T + tid];
        if (use16) {
            const uint4* kp = (const uint4*)(emb16 + (size_t)ki * E);
            #pragma unroll
            for (int c = 0; c < 8; ++c) kr[c] = kp[c];
        } else {
            const float4* kp = (const float4*)(embf + (size_t)ki * E);
            #pragma unroll
            for (int c = 0; c < 8; ++c) {
                const float4 x = kp[2 * c], y = kp[2 * c + 1];
                union { bf16_t h[8]; uint4 v; } u;
                u.h[0] = (bf16_t)x.x; u.h[1] = (bf16_t)x.y; u.h[2] = (bf16_t)x.z; u.h[3] = (bf16_t)x.w;
                u.h[4] = (bf16_t)y.x; u.h[5] = (bf16_t)y.y; u.h[6] = (bf16_t)y.z; u.h[7] = (bf16_t)y.w;
                kr[c] = u.v;
            }
        }
    } else {
        #pragma unroll
        for (int c = 0; c < 8; ++c) kr[c] = make_uint4(0u, 0u, 0u, 0u);
    }

    const int qi = query[b];
    if (tid < 8) {
        uint4 qv;
        if (use16) {
            qv = ((const uint4*)(emb16 + (size_t)qi * E))[tid];
        } else {
            const float4 x = ((const float4*)(embf + (size_t)qi * E))[2 * tid];
            const float4 y = ((const float4*)(embf + (size_t)qi * E))[2 * tid + 1];
            union { bf16_t h[8]; uint4 v; } u;
            u.h[0] = (bf16_t)x.x; u.h[1] = (bf16_t)x.y; u.h[2] = (bf16_t)x.z; u.h[3] = (bf16_t)x.w;
            u.h[4] = (bf16_t)y.x; u.h[5] = (bf16_t)y.y; u.h[6] = (bf16_t)y.z; u.h[7] = (bf16_t)y.w;
            qv = u.v;
        }
        ((uint4*)sQtmp)[tid] = qv;
    }
    if (tid < 64) sW2f[tid] = w2[tid];
    __syncthreads();
    if (tid < 64) sQf[tid] = (float)((const bf16_t*)sQtmp)[tid];
    __syncthreads();

    {
        float* sTmp = (float*)sRaw;
        const int j = tid & 63, ec = tid >> 6;
        float au = 0.f;
        #pragma unroll
        for (int eo = 0; eo < 16; ++eo) {
            const int e = ec * 16 + eo;
            const float w1a = w1[e * 64 + j];
            const float w1b = w1[(64 + e) * 64 + j];
            const float w1c = w1[(128 + e) * 64 + j];
            const float w1d = w1[(192 + e) * 64 + j];
            sTmp[e * 65 + j] = w1b - w1c + sQf[e] * w1d;
            au = fmaf(sQf[e], w1a + w1c, au);
        }
        sUP[tid] = au;
    }
    __syncthreads();
    {
        const float* sTmp = (const float*)sRaw;
        const int e = tid & 63, jc = tid >> 6;
        #pragma unroll
        for (int jo = 0; jo < 16; ++jo) {
            const int j = jc * 16 + jo;
            sMt[j * ROW + e] = (bf16_t)sTmp[e * 65 + j];
        }
    }
    if (tid < 64) sU[tid] = b1[tid] + sUP[tid] + sUP[64 + tid] + sUP[128 + tid] + sUP[192 + tid];
    __syncthreads();

    bf16_t* sK = (bf16_t*)sRaw;
    {
        uint4* dst = (uint4*)(sK + tid * ROW);
        #pragma unroll
        for (int c = 0; c < 8; ++c) dst[c] = kr[c];
    }
    __syncthreads();

    {
        const int n    = lane & 15;
        const int quad = lane >> 4;
        float w2v[4], uv[4];
        bf16x8 bF[4][2];
        #pragma unroll
        for (int nt = 0; nt < 4; ++nt) {
            w2v[nt] = sW2f[nt * 16 + n];
            uv[nt]  = sU[nt * 16 + n];
            bF[nt][0] = *(const bf16x8*)&sMt[(nt * 16 + n) * ROW + quad * 8];
            bF[nt][1] = *(const bf16x8*)&sMt[(nt * 16 + n) * ROW + 32 + quad * 8];
        }
        #pragma unroll
        for (int i = 0; i < 4; ++i) {
            const int mt = wid * 4 + i;
            const bf16x8 a0 = *(const bf16x8*)&sK[(mt * 16 + n) * ROW + quad * 8];
            const bf16x8 a1 = *(const bf16x8*)&sK[(mt * 16 + n) * ROW + 32 + quad * 8];
            float s0 = 0.f, s1 = 0.f, s2 = 0.f, s3 = 0.f;
            #pragma unroll
            for (int nt = 0; nt < 4; ++nt) {
                f32x4 acc = { uv[nt], uv[nt], uv[nt], uv[nt] };
                acc = __builtin_amdgcn_mfma_f32_16x16x32_bf16(a0, bF[nt][0], acc, 0, 0, 0);
                acc = __builtin_amdgcn_mfma_f32_16x16x32_bf16(a1, bF[nt][1], acc, 0, 0, 0);
                s0 = fmaf(fmaxf(acc[0], 0.f), w2v[nt], s0);
                s1 = fmaf(fmaxf(acc[1], 0.f), w2v[nt], s1);
                s2 = fmaf(fmaxf(acc[2], 0.f), w2v[nt], s2);
                s3 = fmaf(fmaxf(acc[3], 0.f), w2v[nt], s3);
            }
            #pragma unroll
            for (int off = 1; off < 16; off <<= 1) {
                s0 += __shfl_xor(s0, off);
                s1 += __shfl_xor(s1, off);
                s2 += __shfl_xor(s2, off);
                s3 += __shfl_xor(s3, off);
            }
            if (n == 0) {
                const int base = mt * 16 + quad * 4;
                sWgt[base + 0] = s0;
                sWgt[base + 1] = s1;
                sWgt[base + 2] = s2;
                sWgt[base + 3] = s3;
            }
        }
    }
    __syncthreads();

    {
        const float score = (tid < T) ? (sWgt[tid] + b2v) : -1e30f;
        float m = score;
        #pragma unroll
        for (int off = 32; off > 0; off >>= 1) m = fmaxf(m, __shfl_xor(m, off));
        if (lane == 0) sRed[wid] = m;
        __syncthreads();
        const float gmax = fmaxf(fmaxf(sRed[0], sRed[1]), fmaxf(sRed[2], sRed[3]));
        const float p = (tid < T) ? __expf(score - gmax) : 0.f;
        float s = p;
        #pragma unroll
        for (int off = 32; off > 0; off >>= 1) s += __shfl_xor(s, off);
        if (lane == 0) sRed[4 + wid] = s;
        __syncthreads();
        const float gsum = sRed[4] + sRed[5] + sRed[6] + sRed[7];
        sWgt[tid] = p / gsum;
    }
    __syncthreads();

    {
        const int e = tid & 63, ch = tid >> 6;
        float a = 0.f;
        #pragma unroll 8
        for (int tt = 0; tt < 64; ++tt) {
            const int t = ch * 64 + tt;
            a = fmaf(sWgt[t], (float)sK[t * ROW + e], a);
        }
        sUP[tid] = a;
    }
    __syncthreads();
    if (tid < 64) sInt[tid] = sUP[tid] + sUP[64 + tid] + sUP[128 + tid] + sUP[192 + tid];
    __syncthreads();

    if (tid < 128) {
        float a = db1[tid];
        #pragma unroll 8
        for (int e = 0; e < 64; ++e) a = fmaf(sInt[e], dw1[e * 128 + tid], a);
        sD1[tid] = fmaxf(a, 0.f);
    }
    __syncthreads();
    if (tid < 64) {
        float a = db2[tid];
        #pragma unroll 8
        for (int i = 0; i < 128; ++i) a = fmaf(sD1[i], dw2[i * 64 + tid], a);
        sD2[tid] = fmaxf(a, 0.f);
    }
    __syncthreads();
    if (tid < 64) {
        float v = sD2[tid] * ow[tid];
        #pragma unroll
        for (int off = 32; off > 0; off >>= 1) v += __shfl_xor(v, off);
        if (tid == 0) out[b] = 1.f / (1.f + __expf(-(v + ob[0])));
    }
}

extern "C" void kernel_launch(void* const* d_in, const int* in_sizes, int n_in,
                              void* d_out, int out_size, void* d_ws, size_t ws_size,
                              hipStream_t stream) {
    const int*   query = (const int*)d_in[0];
    const int*   keys  = (const int*)d_in[1];
    const float* embf  = (const float*)d_in[2];
    const float* w1    = (const float*)d_in[3];
    const float* b1    = (const float*)d_in[4];
    const float* w2    = (const float*)d_in[5];
    const float* b2    = (const float*)d_in[6];
    const float* dw1   = (const float*)d_in[7];
    const float* db1   = (const float*)d_in[8];
    const float* dw2   = (const float*)d_in[9];
    const float* db2   = (const float*)d_in[10];
    const float* ow    = (const float*)d_in[11];
    const float* ob    = (const float*)d_in[12];
    float* out = (float*)d_out;
    const int B        = in_sizes[0];
    const int embElems = in_sizes[2];                  // VOCAB * E
    const size_t WOFF  = 49152;                        // Ap 16K | Ctf 16K | Dtf 16K

    if (ws_size >= WOFF + (size_t)embElems * 2) {
        float*  Ap    = (float*)d_ws;
        float*  Ctf   = (float*)((char*)d_ws + 16384);
        float*  Dtf   = (float*)((char*)d_ws + 32768);
        bf16_t* emb16 = (bf16_t*)((char*)d_ws + WOFF);
        const int n8 = embElems / 8;
        pre_cvt<<<16 + (n8 + 255) / 256, 256, 0, stream>>>(embf, emb16, n8,
                                                           w1, Ap, Ctf, Dtf);
        din_wave<<<B, 64, 0, stream>>>(query, keys, emb16, Ap, Ctf, Dtf,
                                       b1, w2, b2, dw1, db1, dw2, db2,
                                       ow, ob, out, B);
    } else {
        din_kernel<<<B, BDIM, 0, stream>>>(query, keys, embf, (const bf16_t*)d_ws, 0,
                                           w1, b1, w2, b2, dw1, db1, dw2, db2, ow, ob, out);
    }
}

// Round 12
// 146.414 us; speedup vs baseline: 1.2453x; 1.2453x over previous
//
#include <hip/hip_runtime.h>

#define T 200
#define E 64
#define TPAD 256
#define ROW 72
#define BDIM 256

typedef __bf16 bf16_t;
typedef __bf16 bf16x8 __attribute__((ext_vector_type(8)));
typedef float f32x4 __attribute__((ext_vector_type(4)));

// ---- merged pre-pass: blocks 0..15 fold w1; blocks 16.. convert emb ----
__global__ __launch_bounds__(256) void pre_cvt(const float* __restrict__ embf,
                                               bf16_t* __restrict__ emb16, int n8,
                                               const float* __restrict__ w1,
                                               float* __restrict__ Ap,
                                               float* __restrict__ Ctf,
                                               float* __restrict__ Dtf) {
    const int bid = blockIdx.x;
    if (bid < 16) {
        const int idx = bid * 256 + threadIdx.x;      // 0..4095
        const int e = idx >> 6, j = idx & 63;
        const float a = w1[e * 64 + j];
        const float b = w1[(64 + e) * 64 + j];
        const float c = w1[(128 + e) * 64 + j];
        const float d = w1[(192 + e) * 64 + j];
        Ap[e * 64 + j]  = a + c;
        Ctf[j * 64 + e] = b - c;
        Dtf[j * 64 + e] = d;
        return;
    }
    const int i = (bid - 16) * 256 + threadIdx.x;
    if (i >= n8) return;
    const float4* s = (const float4*)embf + (size_t)i * 2;
    const float4 a = s[0], b = s[1];
    union { bf16_t h[8]; uint4 v; } u;
    u.h[0] = (bf16_t)a.x; u.h[1] = (bf16_t)a.y; u.h[2] = (bf16_t)a.z; u.h[3] = (bf16_t)a.w;
    u.h[4] = (bf16_t)b.x; u.h[5] = (bf16_t)b.y; u.h[6] = (bf16_t)b.z; u.h[7] = (bf16_t)b.w;
    ((uint4*)emb16)[i] = u.v;
}

// ===== R12: R11 structure with the register budget fixed =====
// __launch_bounds__(64, 2): min 2 waves/EU -> 256-VGPR budget (R10's proven
// no-spill allocation), while keeping 1-wave blocks (R11 showed 40% occupancy
// vs R10's 18% — but R11's (64,4) budget of 128 forced a 133 MB spill).
__global__ __launch_bounds__(64, 2) void din_wave(
    const int* __restrict__ query,
    const int* __restrict__ keys,
    const bf16_t* __restrict__ emb16,
    const float* __restrict__ Ap,
    const float* __restrict__ Ctf,
    const float* __restrict__ Dtf,
    const float* __restrict__ b1,
    const float* __restrict__ w2,
    const float* __restrict__ b2,
    const float* __restrict__ dw1,
    const float* __restrict__ db1,
    const float* __restrict__ dw2,
    const float* __restrict__ db2,
    const float* __restrict__ ow,
    const float* __restrict__ ob,
    float* __restrict__ out,
    const int nB)
{
    __shared__ __align__(16) char smem[1664];
    const int lane = threadIdx.x;
    const int n    = lane & 15;
    const int quad = lane >> 4;
    const int b    = blockIdx.x;
    if (b >= nB) return;                               // wave-uniform; no barriers

    float* sWgt = (float*)smem;                        // 208 f32 scores/weights
    float* sInt = (float*)(smem + 832);                // 64 f32 interest
    float* sD1  = (float*)(smem + 1088);               // 128 f32 mlp hidden

    // ---- q fragments (bf16, same rounding as before) ----
    const int qi = query[b];
    const bf16x8 q0 = *(const bf16x8*)(emb16 + (size_t)qi * E + quad * 8);
    const bf16x8 q1 = *(const bf16x8*)(emb16 + (size_t)qi * E + 32 + quad * 8);

    // ---- keys for this lane's GEMM rows: t = mt*16 + n (clamped to row 0) ----
    int kidx[13];
    #pragma unroll
    for (int mt = 0; mt < 13; ++mt) {
        const int t = mt * 16 + n;
        kidx[mt] = (t < T) ? keys[b * T + t] : 0;
    }
    // ---- gather A-fragments directly into registers ----
    bf16x8 a0[13], a1[13];
    #pragma unroll
    for (int mt = 0; mt < 13; ++mt) {
        const bf16_t* rp = emb16 + (size_t)kidx[mt] * E;
        a0[mt] = *(const bf16x8*)(rp + quad * 8);
        a1[mt] = *(const bf16x8*)(rp + 32 + quad * 8);
    }

    // ---- u[lane] = sum_e q[e] * Ap[e][lane]  (4 indep chains) ----
    float ua = 0.f, ub = 0.f, uc = 0.f, ud = 0.f;
    #pragma unroll
    for (int e = 0; e < 64; e += 4) {
        ua = fmaf((float)emb16[(size_t)qi * E + e],     Ap[e * 64 + lane],       ua);
        ub = fmaf((float)emb16[(size_t)qi * E + e + 1], Ap[(e + 1) * 64 + lane], ub);
        uc = fmaf((float)emb16[(size_t)qi * E + e + 2], Ap[(e + 2) * 64 + lane], uc);
        ud = fmaf((float)emb16[(size_t)qi * E + e + 3], Ap[(e + 3) * 64 + lane], ud);
    }
    const float u = (ua + ub) + (uc + ud);

    float uv[4], w2v[4];
    #pragma unroll
    for (int nt = 0; nt < 4; ++nt) {
        const int jj = nt * 16 + n;
        uv[nt]  = b1[jj] + __shfl(u, jj);
        w2v[nt] = w2[jj];
    }

    // ---- build B-fragments (M^T) per-lane in registers ----
    bf16x8 bF[4][2];
    #pragma unroll
    for (int nt = 0; nt < 4; ++nt) {
        const int jj = nt * 16 + n;
        const float* cb = Ctf + jj * 64;
        const float* db = Dtf + jj * 64;
        union { bf16_t h[8]; bf16x8 v; } u0, u1;
        #pragma unroll
        for (int x = 0; x < 8; ++x) {
            u0.h[x] = (bf16_t)fmaf((float)q0[x], db[quad * 8 + x],      cb[quad * 8 + x]);
            u1.h[x] = (bf16_t)fmaf((float)q1[x], db[32 + quad * 8 + x], cb[32 + quad * 8 + x]);
        }
        bF[nt][0] = u0.v;
        bF[nt][1] = u1.v;
    }

    // ---- score GEMM (104 MFMA) + 16-lane reduce -> wave-local LDS ----
    #pragma unroll
    for (int mt = 0; mt < 13; ++mt) {
        float s0 = 0.f, s1 = 0.f, s2 = 0.f, s3 = 0.f;
        #pragma unroll
        for (int nt = 0; nt < 4; ++nt) {
            f32x4 acc = { uv[nt], uv[nt], uv[nt], uv[nt] };
            acc = __builtin_amdgcn_mfma_f32_16x16x32_bf16(a0[mt], bF[nt][0], acc, 0, 0, 0);
            acc = __builtin_amdgcn_mfma_f32_16x16x32_bf16(a1[mt], bF[nt][1], acc, 0, 0, 0);
            s0 = fmaf(fmaxf(acc[0], 0.f), w2v[nt], s0);
            s1 = fmaf(fmaxf(acc[1], 0.f), w2v[nt], s1);
            s2 = fmaf(fmaxf(acc[2], 0.f), w2v[nt], s2);
            s3 = fmaf(fmaxf(acc[3], 0.f), w2v[nt], s3);
        }
        #pragma unroll
        for (int off = 1; off < 16; off <<= 1) {
            s0 += __shfl_xor(s0, off);
            s1 += __shfl_xor(s1, off);
            s2 += __shfl_xor(s2, off);
            s3 += __shfl_xor(s3, off);
        }
        if (n == 0) {
            const int base = mt * 16 + quad * 4;
            sWgt[base + 0] = s0;
            sWgt[base + 1] = s1;
            sWgt[base + 2] = s2;
            sWgt[base + 3] = s3;
        }
    }
    asm volatile("s_waitcnt lgkmcnt(0)" ::: "memory");
    __builtin_amdgcn_sched_barrier(0);

    // ---- wave softmax, normalization folded ----
    {
        const float b2v = b2[0];
        const float x0 = sWgt[lane] + b2v;
        const float x1 = sWgt[64 + lane] + b2v;
        const float x2 = sWgt[128 + lane] + b2v;
        const float x3 = (lane < 8) ? (sWgt[192 + lane] + b2v) : -1e30f;
        float m = fmaxf(fmaxf(x0, x1), fmaxf(x2, x3));
        #pragma unroll
        for (int off = 32; off > 0; off >>= 1) m = fmaxf(m, __shfl_xor(m, off));
        const float p0 = __expf(x0 - m);
        const float p1 = __expf(x1 - m);
        const float p2 = __expf(x2 - m);
        const float p3 = (lane < 8) ? __expf(x3 - m) : 0.f;
        float s = ((p0 + p1) + (p2 + p3));
        #pragma unroll
        for (int off = 32; off > 0; off >>= 1) s += __shfl_xor(s, off);
        const float inv = 1.f / s;
        sWgt[lane]       = p0 * inv;
        sWgt[64 + lane]  = p1 * inv;
        sWgt[128 + lane] = p2 * inv;
        if (lane < 8) sWgt[192 + lane] = p3 * inv;
    }
    asm volatile("s_waitcnt lgkmcnt(0)" ::: "memory");
    __builtin_amdgcn_sched_barrier(0);

    // ---- interest from the SAME register fragments ----
    {
        float pa[8], pb[8];
        #pragma unroll
        for (int x = 0; x < 8; ++x) { pa[x] = 0.f; pb[x] = 0.f; }
        #pragma unroll
        for (int mt = 0; mt < 13; ++mt) {
            const int t = mt * 16 + n;
            const float wt = (t < T) ? sWgt[t] : 0.f;
            #pragma unroll
            for (int x = 0; x < 8; ++x) {
                pa[x] = fmaf(wt, (float)a0[mt][x], pa[x]);
                pb[x] = fmaf(wt, (float)a1[mt][x], pb[x]);
            }
        }
        #pragma unroll
        for (int x = 0; x < 8; ++x) {
            #pragma unroll
            for (int off = 1; off < 16; off <<= 1) {
                pa[x] += __shfl_xor(pa[x], off);
                pb[x] += __shfl_xor(pb[x], off);
            }
        }
        if (n == 0) {
            #pragma unroll
            for (int x = 0; x < 8; ++x) {
                sInt[quad * 8 + x]      = pa[x];
                sInt[32 + quad * 8 + x] = pb[x];
            }
        }
    }
    asm volatile("s_waitcnt lgkmcnt(0)" ::: "memory");
    __builtin_amdgcn_sched_barrier(0);

    // ---- deep MLP 64 -> 128 (2 outputs/lane, 2 chains each) ----
    {
        float d1a0 = db1[lane], d1a1 = 0.f;
        float d1b0 = db1[64 + lane], d1b1 = 0.f;
        #pragma unroll
        for (int e = 0; e < 64; e += 2) {
            const float ie0 = sInt[e], ie1 = sInt[e + 1];
            d1a0 = fmaf(ie0, dw1[e * 128 + lane], d1a0);
            d1a1 = fmaf(ie1, dw1[(e + 1) * 128 + lane], d1a1);
            d1b0 = fmaf(ie0, dw1[e * 128 + 64 + lane], d1b0);
            d1b1 = fmaf(ie1, dw1[(e + 1) * 128 + 64 + lane], d1b1);
        }
        sD1[lane]      = fmaxf(d1a0 + d1a1, 0.f);
        sD1[64 + lane] = fmaxf(d1b0 + d1b1, 0.f);
    }
    asm volatile("s_waitcnt lgkmcnt(0)" ::: "memory");
    __builtin_amdgcn_sched_barrier(0);

    // ---- 128 -> 64 -> 1 (4 chains) ----
    {
        float o0 = db2[lane], o1 = 0.f, o2 = 0.f, o3 = 0.f;
        #pragma unroll
        for (int i = 0; i < 128; i += 4) {
            o0 = fmaf(sD1[i],     dw2[i * 64 + lane],       o0);
            o1 = fmaf(sD1[i + 1], dw2[(i + 1) * 64 + lane], o1);
            o2 = fmaf(sD1[i + 2], dw2[(i + 2) * 64 + lane], o2);
            o3 = fmaf(sD1[i + 3], dw2[(i + 3) * 64 + lane], o3);
        }
        float v = fmaxf((o0 + o1) + (o2 + o3), 0.f) * ow[lane];
        #pragma unroll
        for (int off = 32; off > 0; off >>= 1) v += __shfl_xor(v, off);
        if (lane == 0) out[b] = 1.f / (1.f + __expf(-(v + ob[0])));
    }
}

// ============ fallback: verified kernel (ws too small; fp32 path) ============
__global__ __launch_bounds__(BDIM, 3) void din_kernel(
    const int* __restrict__ query,
    const int* __restrict__ keys,
    const float* __restrict__ embf,
    const bf16_t* __restrict__ emb16,
    const int use16,
    const float* __restrict__ w1,
    const float* __restrict__ b1,
    const float* __restrict__ w2,
    const float* __restrict__ b2,
    const float* __restrict__ dw1,
    const float* __restrict__ db1,
    const float* __restrict__ dw2,
    const float* __restrict__ db2,
    const float* __restrict__ ow,
    const float* __restrict__ ob,
    float* __restrict__ out)
{
    __shared__ __align__(16) char sRaw[TPAD * ROW * 2];
    __shared__ __align__(16) bf16_t sMt[64 * ROW];
    __shared__ float sU[64];
    __shared__ float sUP[256];
    __shared__ float sW2f[64];
    __shared__ float sWgt[256];
    __shared__ float sQf[64];
    __shared__ __align__(16) char sQtmp[128];
    __shared__ float sRed[8];
    __shared__ float sInt[64];
    __shared__ float sD1[128];
    __shared__ float sD2[64];

    const int tid  = threadIdx.x;
    const int lane = tid & 63;
    const int wid  = tid >> 6;
    const int b    = blockIdx.x;
    const float b2v = b2[0];

    uint4 kr[8];
    if (tid < T) {
        const int ki = keys[b * T + tid];
        if (use16) {
            const uint4* kp = (const uint4*)(emb16 + (size_t)ki * E);
            #pragma unroll
            for (int c = 0; c < 8; ++c) kr[c] = kp[c];
        } else {
            const float4* kp = (const float4*)(embf + (size_t)ki * E);
            #pragma unroll
            for (int c = 0; c < 8; ++c) {
                const float4 x = kp[2 * c], y = kp[2 * c + 1];
                union { bf16_t h[8]; uint4 v; } u;
                u.h[0] = (bf16_t)x.x; u.h[1] = (bf16_t)x.y; u.h[2] = (bf16_t)x.z; u.h[3] = (bf16_t)x.w;
                u.h[4] = (bf16_t)y.x; u.h[5] = (bf16_t)y.y; u.h[6] = (bf16_t)y.z; u.h[7] = (bf16_t)y.w;
                kr[c] = u.v;
            }
        }
    } else {
        #pragma unroll
        for (int c = 0; c < 8; ++c) kr[c] = make_uint4(0u, 0u, 0u, 0u);
    }

    const int qi = query[b];
    if (tid < 8) {
        uint4 qv;
        if (use16) {
            qv = ((const uint4*)(emb16 + (size_t)qi * E))[tid];
        } else {
            const float4 x = ((const float4*)(embf + (size_t)qi * E))[2 * tid];
            const float4 y = ((const float4*)(embf + (size_t)qi * E))[2 * tid + 1];
            union { bf16_t h[8]; uint4 v; } u;
            u.h[0] = (bf16_t)x.x; u.h[1] = (bf16_t)x.y; u.h[2] = (bf16_t)x.z; u.h[3] = (bf16_t)x.w;
            u.h[4] = (bf16_t)y.x; u.h[5] = (bf16_t)y.y; u.h[6] = (bf16_t)y.z; u.h[7] = (bf16_t)y.w;
            qv = u.v;
        }
        ((uint4*)sQtmp)[tid] = qv;
    }
    if (tid < 64) sW2f[tid] = w2[tid];
    __syncthreads();
    if (tid < 64) sQf[tid] = (float)((const bf16_t*)sQtmp)[tid];
    __syncthreads();

    {
        float* sTmp = (float*)sRaw;
        const int j = tid & 63, ec = tid >> 6;
        float au = 0.f;
        #pragma unroll
        for (int eo = 0; eo < 16; ++eo) {
            const int e = ec * 16 + eo;
            const float w1a = w1[e * 64 + j];
            const float w1b = w1[(64 + e) * 64 + j];
            const float w1c = w1[(128 + e) * 64 + j];
            const float w1d = w1[(192 + e) * 64 + j];
            sTmp[e * 65 + j] = w1b - w1c + sQf[e] * w1d;
            au = fmaf(sQf[e], w1a + w1c, au);
        }
        sUP[tid] = au;
    }
    __syncthreads();
    {
        const float* sTmp = (const float*)sRaw;
        const int e = tid & 63, jc = tid >> 6;
        #pragma unroll
        for (int jo = 0; jo < 16; ++jo) {
            const int j = jc * 16 + jo;
            sMt[j * ROW + e] = (bf16_t)sTmp[e * 65 + j];
        }
    }
    if (tid < 64) sU[tid] = b1[tid] + sUP[tid] + sUP[64 + tid] + sUP[128 + tid] + sUP[192 + tid];
    __syncthreads();

    bf16_t* sK = (bf16_t*)sRaw;
    {
        uint4* dst = (uint4*)(sK + tid * ROW);
        #pragma unroll
        for (int c = 0; c < 8; ++c) dst[c] = kr[c];
    }
    __syncthreads();

    {
        const int n    = lane & 15;
        const int quad = lane >> 4;
        float w2v[4], uv[4];
        bf16x8 bF[4][2];
        #pragma unroll
        for (int nt = 0; nt < 4; ++nt) {
            w2v[nt] = sW2f[nt * 16 + n];
            uv[nt]  = sU[nt * 16 + n];
            bF[nt][0] = *(const bf16x8*)&sMt[(nt * 16 + n) * ROW + quad * 8];
            bF[nt][1] = *(const bf16x8*)&sMt[(nt * 16 + n) * ROW + 32 + quad * 8];
        }
        #pragma unroll
        for (int i = 0; i < 4; ++i) {
            const int mt = wid * 4 + i;
            const bf16x8 a0 = *(const bf16x8*)&sK[(mt * 16 + n) * ROW + quad * 8];
            const bf16x8 a1 = *(const bf16x8*)&sK[(mt * 16 + n) * ROW + 32 + quad * 8];
            float s0 = 0.f, s1 = 0.f, s2 = 0.f, s3 = 0.f;
            #pragma unroll
            for (int nt = 0; nt < 4; ++nt) {
                f32x4 acc = { uv[nt], uv[nt], uv[nt], uv[nt] };
                acc = __builtin_amdgcn_mfma_f32_16x16x32_bf16(a0, bF[nt][0], acc, 0, 0, 0);
                acc = __builtin_amdgcn_mfma_f32_16x16x32_bf16(a1, bF[nt][1], acc, 0, 0, 0);
                s0 = fmaf(fmaxf(acc[0], 0.f), w2v[nt], s0);
                s1 = fmaf(fmaxf(acc[1], 0.f), w2v[nt], s1);
                s2 = fmaf(fmaxf(acc[2], 0.f), w2v[nt], s2);
                s3 = fmaf(fmaxf(acc[3], 0.f), w2v[nt], s3);
            }
            #pragma unroll
            for (int off = 1; off < 16; off <<= 1) {
                s0 += __shfl_xor(s0, off);
                s1 += __shfl_xor(s1, off);
                s2 += __shfl_xor(s2, off);
                s3 += __shfl_xor(s3, off);
            }
            if (n == 0) {
                const int base = mt * 16 + quad * 4;
                sWgt[base + 0] = s0;
                sWgt[base + 1] = s1;
                sWgt[base + 2] = s2;
                sWgt[base + 3] = s3;
            }
        }
    }
    __syncthreads();

    {
        const float score = (tid < T) ? (sWgt[tid] + b2v) : -1e30f;
        float m = score;
        #pragma unroll
        for (int off = 32; off > 0; off >>= 1) m = fmaxf(m, __shfl_xor(m, off));
        if (lane == 0) sRed[wid] = m;
        __syncthreads();
        const float gmax = fmaxf(fmaxf(sRed[0], sRed[1]), fmaxf(sRed[2], sRed[3]));
        const float p = (tid < T) ? __expf(score - gmax) : 0.f;
        float s = p;
        #pragma unroll
        for (int off = 32; off > 0; off >>= 1) s += __shfl_xor(s, off);
        if (lane == 0) sRed[4 + wid] = s;
        __syncthreads();
        const float gsum = sRed[4] + sRed[5] + sRed[6] + sRed[7];
        sWgt[tid] = p / gsum;
    }
    __syncthreads();

    {
        const int e = tid & 63, ch = tid >> 6;
        float a = 0.f;
        #pragma unroll 8
        for (int tt = 0; tt < 64; ++tt) {
            const int t = ch * 64 + tt;
            a = fmaf(sWgt[t], (float)sK[t * ROW + e], a);
        }
        sUP[tid] = a;
    }
    __syncthreads();
    if (tid < 64) sInt[tid] = sUP[tid] + sUP[64 + tid] + sUP[128 + tid] + sUP[192 + tid];
    __syncthreads();

    if (tid < 128) {
        float a = db1[tid];
        #pragma unroll 8
        for (int e = 0; e < 64; ++e) a = fmaf(sInt[e], dw1[e * 128 + tid], a);
        sD1[tid] = fmaxf(a, 0.f);
    }
    __syncthreads();
    if (tid < 64) {
        float a = db2[tid];
        #pragma unroll 8
        for (int i = 0; i < 128; ++i) a = fmaf(sD1[i], dw2[i * 64 + tid], a);
        sD2[tid] = fmaxf(a, 0.f);
    }
    __syncthreads();
    if (tid < 64) {
        float v = sD2[tid] * ow[tid];
        #pragma unroll
        for (int off = 32; off > 0; off >>= 1) v += __shfl_xor(v, off);
        if (tid == 0) out[b] = 1.f / (1.f + __expf(-(v + ob[0])));
    }
}

extern "C" void kernel_launch(void* const* d_in, const int* in_sizes, int n_in,
                              void* d_out, int out_size, void* d_ws, size_t ws_size,
                              hipStream_t stream) {
    const int*   query = (const int*)d_in[0];
    const int*   keys  = (const int*)d_in[1];
    const float* embf  = (const float*)d_in[2];
    const float* w1    = (const float*)d_in[3];
    const float* b1    = (const float*)d_in[4];
    const float* w2    = (const float*)d_in[5];
    const float* b2    = (const float*)d_in[6];
    const float* dw1   = (const float*)d_in[7];
    const float* db1   = (const float*)d_in[8];
    const float* dw2   = (const float*)d_in[9];
    const float* db2   = (const float*)d_in[10];
    const float* ow    = (const float*)d_in[11];
    const float* ob    = (const float*)d_in[12];
    float* out = (float*)d_out;
    const int B        = in_sizes[0];
    const int embElems = in_sizes[2];                  // VOCAB * E
    const size_t WOFF  = 49152;                        // Ap 16K | Ctf 16K | Dtf 16K

    if (ws_size >= WOFF + (size_t)embElems * 2) {
        float*  Ap    = (float*)d_ws;
        float*  Ctf   = (float*)((char*)d_ws + 16384);
        float*  Dtf   = (float*)((char*)d_ws + 32768);
        bf16_t* emb16 = (bf16_t*)((char*)d_ws + WOFF);
        const int n8 = embElems / 8;
        pre_cvt<<<16 + (n8 + 255) / 256, 256, 0, stream>>>(embf, emb16, n8,
                                                           w1, Ap, Ctf, Dtf);
        din_wave<<<B, 64, 0, stream>>>(query, keys, emb16, Ap, Ctf, Dtf,
                                       b1, w2, b2, dw1, db1, dw2, db2,
                                       ow, ob, out, B);
    } else {
        din_kernel<<<B, BDIM, 0, stream>>>(query, keys, embf, (const bf16_t*)d_ws, 0,
                                           w1, b1, w2, b2, dw1, db1, dw2, db2, ow, ob, out);
    }
}

// Round 13
// 145.521 us; speedup vs baseline: 1.2530x; 1.0061x over previous
//
#include <hip/hip_runtime.h>

#define T 200
#define E 64
#define TPAD 256
#define ROW 72
#define BDIM 256

typedef __bf16 bf16_t;
typedef __bf16 bf16x8 __attribute__((ext_vector_type(8)));
typedef float f32x4 __attribute__((ext_vector_type(4)));

// ---- merged pre-pass: blocks 0..15 fold w1; blocks 16.. convert emb ----
__global__ __launch_bounds__(256) void pre_cvt(const float* __restrict__ embf,
                                               bf16_t* __restrict__ emb16, int n8,
                                               const float* __restrict__ w1,
                                               float* __restrict__ Ap,
                                               float* __restrict__ Ctf,
                                               float* __restrict__ Dtf) {
    const int bid = blockIdx.x;
    if (bid < 16) {
        const int idx = bid * 256 + threadIdx.x;      // 0..4095
        const int e = idx >> 6, j = idx & 63;
        const float a = w1[e * 64 + j];
        const float b = w1[(64 + e) * 64 + j];
        const float c = w1[(128 + e) * 64 + j];
        const float d = w1[(192 + e) * 64 + j];
        Ap[e * 64 + j]  = a + c;
        Ctf[j * 64 + e] = b - c;
        Dtf[j * 64 + e] = d;
        return;
    }
    const int i = (bid - 16) * 256 + threadIdx.x;
    if (i >= n8) return;
    const float4* s = (const float4*)embf + (size_t)i * 2;
    const float4 a = s[0], b = s[1];
    union { bf16_t h[8]; uint4 v; } u;
    u.h[0] = (bf16_t)a.x; u.h[1] = (bf16_t)a.y; u.h[2] = (bf16_t)a.z; u.h[3] = (bf16_t)a.w;
    u.h[4] = (bf16_t)b.x; u.h[5] = (bf16_t)b.y; u.h[6] = (bf16_t)b.z; u.h[7] = (bf16_t)b.w;
    ((uint4*)emb16)[i] = u.v;
}

// ===== R13: R12 with DS-only phase fences =====
// Phase boundaries were asm("s_waitcnt lgkmcnt(0)":::"memory") + sched_barrier(0),
// which pinned ~320 global weight loads (Ap/Ctf/Dtf/dw1/dw2) inside their phases
// and serialized their L2 latency phase-by-phase. Now: waitcnt WITHOUT the
// memory clobber + sched_barrier(0x11) (ALU|VMEM may cross; DS may not).
// Cross-lane handoffs are same-LDS-array (alias-ordered at IR); DS pinned at
// sched; HW executes same-wave DS in order -> numerics and ordering unchanged,
// but the compiler may now hoist/overlap global loads across phases.
__global__ __launch_bounds__(64, 2) void din_wave(
    const int* __restrict__ query,
    const int* __restrict__ keys,
    const bf16_t* __restrict__ emb16,
    const float* __restrict__ Ap,
    const float* __restrict__ Ctf,
    const float* __restrict__ Dtf,
    const float* __restrict__ b1,
    const float* __restrict__ w2,
    const float* __restrict__ b2,
    const float* __restrict__ dw1,
    const float* __restrict__ db1,
    const float* __restrict__ dw2,
    const float* __restrict__ db2,
    const float* __restrict__ ow,
    const float* __restrict__ ob,
    float* __restrict__ out,
    const int nB)
{
    __shared__ __align__(16) char smem[1664];
    const int lane = threadIdx.x;
    const int n    = lane & 15;
    const int quad = lane >> 4;
    const int b    = blockIdx.x;
    if (b >= nB) return;                               // wave-uniform; no barriers

    float* sWgt = (float*)smem;                        // 208 f32 scores/weights
    float* sInt = (float*)(smem + 832);                // 64 f32 interest
    float* sD1  = (float*)(smem + 1088);               // 128 f32 mlp hidden

    // ---- q fragments (bf16, same rounding as before) ----
    const int qi = query[b];
    const bf16x8 q0 = *(const bf16x8*)(emb16 + (size_t)qi * E + quad * 8);
    const bf16x8 q1 = *(const bf16x8*)(emb16 + (size_t)qi * E + 32 + quad * 8);

    // ---- keys for this lane's GEMM rows: t = mt*16 + n (clamped to row 0) ----
    int kidx[13];
    #pragma unroll
    for (int mt = 0; mt < 13; ++mt) {
        const int t = mt * 16 + n;
        kidx[mt] = (t < T) ? keys[b * T + t] : 0;
    }
    // ---- gather A-fragments directly into registers ----
    bf16x8 a0[13], a1[13];
    #pragma unroll
    for (int mt = 0; mt < 13; ++mt) {
        const bf16_t* rp = emb16 + (size_t)kidx[mt] * E;
        a0[mt] = *(const bf16x8*)(rp + quad * 8);
        a1[mt] = *(const bf16x8*)(rp + 32 + quad * 8);
    }

    // ---- u[lane] = sum_e q[e] * Ap[e][lane]  (4 indep chains) ----
    float ua = 0.f, ub = 0.f, uc = 0.f, ud = 0.f;
    #pragma unroll
    for (int e = 0; e < 64; e += 4) {
        ua = fmaf((float)emb16[(size_t)qi * E + e],     Ap[e * 64 + lane],       ua);
        ub = fmaf((float)emb16[(size_t)qi * E + e + 1], Ap[(e + 1) * 64 + lane], ub);
        uc = fmaf((float)emb16[(size_t)qi * E + e + 2], Ap[(e + 2) * 64 + lane], uc);
        ud = fmaf((float)emb16[(size_t)qi * E + e + 3], Ap[(e + 3) * 64 + lane], ud);
    }
    const float u = (ua + ub) + (uc + ud);

    float uv[4], w2v[4];
    #pragma unroll
    for (int nt = 0; nt < 4; ++nt) {
        const int jj = nt * 16 + n;
        uv[nt]  = b1[jj] + __shfl(u, jj);
        w2v[nt] = w2[jj];
    }

    // ---- build B-fragments (M^T) per-lane in registers ----
    bf16x8 bF[4][2];
    #pragma unroll
    for (int nt = 0; nt < 4; ++nt) {
        const int jj = nt * 16 + n;
        const float* cb = Ctf + jj * 64;
        const float* db = Dtf + jj * 64;
        union { bf16_t h[8]; bf16x8 v; } u0, u1;
        #pragma unroll
        for (int x = 0; x < 8; ++x) {
            u0.h[x] = (bf16_t)fmaf((float)q0[x], db[quad * 8 + x],      cb[quad * 8 + x]);
            u1.h[x] = (bf16_t)fmaf((float)q1[x], db[32 + quad * 8 + x], cb[32 + quad * 8 + x]);
        }
        bF[nt][0] = u0.v;
        bF[nt][1] = u1.v;
    }

    // ---- score GEMM (104 MFMA) + 16-lane reduce -> wave-local LDS ----
    #pragma unroll
    for (int mt = 0; mt < 13; ++mt) {
        float s0 = 0.f, s1 = 0.f, s2 = 0.f, s3 = 0.f;
        #pragma unroll
        for (int nt = 0; nt < 4; ++nt) {
            f32x4 acc = { uv[nt], uv[nt], uv[nt], uv[nt] };
            acc = __builtin_amdgcn_mfma_f32_16x16x32_bf16(a0[mt], bF[nt][0], acc, 0, 0, 0);
            acc = __builtin_amdgcn_mfma_f32_16x16x32_bf16(a1[mt], bF[nt][1], acc, 0, 0, 0);
            s0 = fmaf(fmaxf(acc[0], 0.f), w2v[nt], s0);
            s1 = fmaf(fmaxf(acc[1], 0.f), w2v[nt], s1);
            s2 = fmaf(fmaxf(acc[2], 0.f), w2v[nt], s2);
            s3 = fmaf(fmaxf(acc[3], 0.f), w2v[nt], s3);
        }
        #pragma unroll
        for (int off = 1; off < 16; off <<= 1) {
            s0 += __shfl_xor(s0, off);
            s1 += __shfl_xor(s1, off);
            s2 += __shfl_xor(s2, off);
            s3 += __shfl_xor(s3, off);
        }
        if (n == 0) {
            const int base = mt * 16 + quad * 4;
            sWgt[base + 0] = s0;
            sWgt[base + 1] = s1;
            sWgt[base + 2] = s2;
            sWgt[base + 3] = s3;
        }
    }
    asm volatile("s_waitcnt lgkmcnt(0)");
    __builtin_amdgcn_sched_barrier(0x11);              // DS pinned; ALU/VMEM may cross

    // ---- wave softmax, normalization folded ----
    {
        const float b2v = b2[0];
        const float x0 = sWgt[lane] + b2v;
        const float x1 = sWgt[64 + lane] + b2v;
        const float x2 = sWgt[128 + lane] + b2v;
        const float x3 = (lane < 8) ? (sWgt[192 + lane] + b2v) : -1e30f;
        float m = fmaxf(fmaxf(x0, x1), fmaxf(x2, x3));
        #pragma unroll
        for (int off = 32; off > 0; off >>= 1) m = fmaxf(m, __shfl_xor(m, off));
        const float p0 = __expf(x0 - m);
        const float p1 = __expf(x1 - m);
        const float p2 = __expf(x2 - m);
        const float p3 = (lane < 8) ? __expf(x3 - m) : 0.f;
        float s = ((p0 + p1) + (p2 + p3));
        #pragma unroll
        for (int off = 32; off > 0; off >>= 1) s += __shfl_xor(s, off);
        const float inv = 1.f / s;
        sWgt[lane]       = p0 * inv;
        sWgt[64 + lane]  = p1 * inv;
        sWgt[128 + lane] = p2 * inv;
        if (lane < 8) sWgt[192 + lane] = p3 * inv;
    }
    asm volatile("s_waitcnt lgkmcnt(0)");
    __builtin_amdgcn_sched_barrier(0x11);

    // ---- interest from the SAME register fragments ----
    {
        float pa[8], pb[8];
        #pragma unroll
        for (int x = 0; x < 8; ++x) { pa[x] = 0.f; pb[x] = 0.f; }
        #pragma unroll
        for (int mt = 0; mt < 13; ++mt) {
            const int t = mt * 16 + n;
            const float wt = (t < T) ? sWgt[t] : 0.f;
            #pragma unroll
            for (int x = 0; x < 8; ++x) {
                pa[x] = fmaf(wt, (float)a0[mt][x], pa[x]);
                pb[x] = fmaf(wt, (float)a1[mt][x], pb[x]);
            }
        }
        #pragma unroll
        for (int x = 0; x < 8; ++x) {
            #pragma unroll
            for (int off = 1; off < 16; off <<= 1) {
                pa[x] += __shfl_xor(pa[x], off);
                pb[x] += __shfl_xor(pb[x], off);
            }
        }
        if (n == 0) {
            #pragma unroll
            for (int x = 0; x < 8; ++x) {
                sInt[quad * 8 + x]      = pa[x];
                sInt[32 + quad * 8 + x] = pb[x];
            }
        }
    }
    asm volatile("s_waitcnt lgkmcnt(0)");
    __builtin_amdgcn_sched_barrier(0x11);

    // ---- deep MLP 64 -> 128 (2 outputs/lane, 2 chains each) ----
    {
        float d1a0 = db1[lane], d1a1 = 0.f;
        float d1b0 = db1[64 + lane], d1b1 = 0.f;
        #pragma unroll
        for (int e = 0; e < 64; e += 2) {
            const float ie0 = sInt[e], ie1 = sInt[e + 1];
            d1a0 = fmaf(ie0, dw1[e * 128 + lane], d1a0);
            d1a1 = fmaf(ie1, dw1[(e + 1) * 128 + lane], d1a1);
            d1b0 = fmaf(ie0, dw1[e * 128 + 64 + lane], d1b0);
            d1b1 = fmaf(ie1, dw1[(e + 1) * 128 + 64 + lane], d1b1);
        }
        sD1[lane]      = fmaxf(d1a0 + d1a1, 0.f);
        sD1[64 + lane] = fmaxf(d1b0 + d1b1, 0.f);
    }
    asm volatile("s_waitcnt lgkmcnt(0)");
    __builtin_amdgcn_sched_barrier(0x11);

    // ---- 128 -> 64 -> 1 (4 chains) ----
    {
        float o0 = db2[lane], o1 = 0.f, o2 = 0.f, o3 = 0.f;
        #pragma unroll
        for (int i = 0; i < 128; i += 4) {
            o0 = fmaf(sD1[i],     dw2[i * 64 + lane],       o0);
            o1 = fmaf(sD1[i + 1], dw2[(i + 1) * 64 + lane], o1);
            o2 = fmaf(sD1[i + 2], dw2[(i + 2) * 64 + lane], o2);
            o3 = fmaf(sD1[i + 3], dw2[(i + 3) * 64 + lane], o3);
        }
        float v = fmaxf((o0 + o1) + (o2 + o3), 0.f) * ow[lane];
        #pragma unroll
        for (int off = 32; off > 0; off >>= 1) v += __shfl_xor(v, off);
        if (lane == 0) out[b] = 1.f / (1.f + __expf(-(v + ob[0])));
    }
}

// ============ fallback: verified kernel (ws too small; fp32 path) ============
__global__ __launch_bounds__(BDIM, 3) void din_kernel(
    const int* __restrict__ query,
    const int* __restrict__ keys,
    const float* __restrict__ embf,
    const bf16_t* __restrict__ emb16,
    const int use16,
    const float* __restrict__ w1,
    const float* __restrict__ b1,
    const float* __restrict__ w2,
    const float* __restrict__ b2,
    const float* __restrict__ dw1,
    const float* __restrict__ db1,
    const float* __restrict__ dw2,
    const float* __restrict__ db2,
    const float* __restrict__ ow,
    const float* __restrict__ ob,
    float* __restrict__ out)
{
    __shared__ __align__(16) char sRaw[TPAD * ROW * 2];
    __shared__ __align__(16) bf16_t sMt[64 * ROW];
    __shared__ float sU[64];
    __shared__ float sUP[256];
    __shared__ float sW2f[64];
    __shared__ float sWgt[256];
    __shared__ float sQf[64];
    __shared__ __align__(16) char sQtmp[128];
    __shared__ float sRed[8];
    __shared__ float sInt[64];
    __shared__ float sD1[128];
    __shared__ float sD2[64];

    const int tid  = threadIdx.x;
    const int lane = tid & 63;
    const int wid  = tid >> 6;
    const int b    = blockIdx.x;
    const float b2v = b2[0];

    uint4 kr[8];
    if (tid < T) {
        const int ki = keys[b * T + tid];
        if (use16) {
            const uint4* kp = (const uint4*)(emb16 + (size_t)ki * E);
            #pragma unroll
            for (int c = 0; c < 8; ++c) kr[c] = kp[c];
        } else {
            const float4* kp = (const float4*)(embf + (size_t)ki * E);
            #pragma unroll
            for (int c = 0; c < 8; ++c) {
                const float4 x = kp[2 * c], y = kp[2 * c + 1];
                union { bf16_t h[8]; uint4 v; } u;
                u.h[0] = (bf16_t)x.x; u.h[1] = (bf16_t)x.y; u.h[2] = (bf16_t)x.z; u.h[3] = (bf16_t)x.w;
                u.h[4] = (bf16_t)y.x; u.h[5] = (bf16_t)y.y; u.h[6] = (bf16_t)y.z; u.h[7] = (bf16_t)y.w;
                kr[c] = u.v;
            }
        }
    } else {
        #pragma unroll
        for (int c = 0; c < 8; ++c) kr[c] = make_uint4(0u, 0u, 0u, 0u);
    }

    const int qi = query[b];
    if (tid < 8) {
        uint4 qv;
        if (use16) {
            qv = ((const uint4*)(emb16 + (size_t)qi * E))[tid];
        } else {
            const float4 x = ((const float4*)(embf + (size_t)qi * E))[2 * tid];
            const float4 y = ((const float4*)(embf + (size_t)qi * E))[2 * tid + 1];
            union { bf16_t h[8]; uint4 v; } u;
            u.h[0] = (bf16_t)x.x; u.h[1] = (bf16_t)x.y; u.h[2] = (bf16_t)x.z; u.h[3] = (bf16_t)x.w;
            u.h[4] = (bf16_t)y.x; u.h[5] = (bf16_t)y.y; u.h[6] = (bf16_t)y.z; u.h[7] = (bf16_t)y.w;
            qv = u.v;
        }
        ((uint4*)sQtmp)[tid] = qv;
    }
    if (tid < 64) sW2f[tid] = w2[tid];
    __syncthreads();
    if (tid < 64) sQf[tid] = (float)((const bf16_t*)sQtmp)[tid];
    __syncthreads();

    {
        float* sTmp = (float*)sRaw;
        const int j = tid & 63, ec = tid >> 6;
        float au = 0.f;
        #pragma unroll
        for (int eo = 0; eo < 16; ++eo) {
            const int e = ec * 16 + eo;
            const float w1a = w1[e * 64 + j];
            const float w1b = w1[(64 + e) * 64 + j];
            const float w1c = w1[(128 + e) * 64 + j];
            const float w1d = w1[(192 + e) * 64 + j];
            sTmp[e * 65 + j] = w1b - w1c + sQf[e] * w1d;
            au = fmaf(sQf[e], w1a + w1c, au);
        }
        sUP[tid] = au;
    }
    __syncthreads();
    {
        const float* sTmp = (const float*)sRaw;
        const int e = tid & 63, jc = tid >> 6;
        #pragma unroll
        for (int jo = 0; jo < 16; ++jo) {
            const int j = jc * 16 + jo;
            sMt[j * ROW + e] = (bf16_t)sTmp[e * 65 + j];
        }
    }
    if (tid < 64) sU[tid] = b1[tid] + sUP[tid] + sUP[64 + tid] + sUP[128 + tid] + sUP[192 + tid];
    __syncthreads();

    bf16_t* sK = (bf16_t*)sRaw;
    {
        uint4* dst = (uint4*)(sK + tid * ROW);
        #pragma unroll
        for (int c = 0; c < 8; ++c) dst[c] = kr[c];
    }
    __syncthreads();

    {
        const int n    = lane & 15;
        const int quad = lane >> 4;
        float w2v[4], uv[4];
        bf16x8 bF[4][2];
        #pragma unroll
        for (int nt = 0; nt < 4; ++nt) {
            w2v[nt] = sW2f[nt * 16 + n];
            uv[nt]  = sU[nt * 16 + n];
            bF[nt][0] = *(const bf16x8*)&sMt[(nt * 16 + n) * ROW + quad * 8];
            bF[nt][1] = *(const bf16x8*)&sMt[(nt * 16 + n) * ROW + 32 + quad * 8];
        }
        #pragma unroll
        for (int i = 0; i < 4; ++i) {
            const int mt = wid * 4 + i;
            const bf16x8 a0 = *(const bf16x8*)&sK[(mt * 16 + n) * ROW + quad * 8];
            const bf16x8 a1 = *(const bf16x8*)&sK[(mt * 16 + n) * ROW + 32 + quad * 8];
            float s0 = 0.f, s1 = 0.f, s2 = 0.f, s3 = 0.f;
            #pragma unroll
            for (int nt = 0; nt < 4; ++nt) {
                f32x4 acc = { uv[nt], uv[nt], uv[nt], uv[nt] };
                acc = __builtin_amdgcn_mfma_f32_16x16x32_bf16(a0, bF[nt][0], acc, 0, 0, 0);
                acc = __builtin_amdgcn_mfma_f32_16x16x32_bf16(a1, bF[nt][1], acc, 0, 0, 0);
                s0 = fmaf(fmaxf(acc[0], 0.f), w2v[nt], s0);
                s1 = fmaf(fmaxf(acc[1], 0.f), w2v[nt], s1);
                s2 = fmaf(fmaxf(acc[2], 0.f), w2v[nt], s2);
                s3 = fmaf(fmaxf(acc[3], 0.f), w2v[nt], s3);
            }
            #pragma unroll
            for (int off = 1; off < 16; off <<= 1) {
                s0 += __shfl_xor(s0, off);
                s1 += __shfl_xor(s1, off);
                s2 += __shfl_xor(s2, off);
                s3 += __shfl_xor(s3, off);
            }
            if (n == 0) {
                const int base = mt * 16 + quad * 4;
                sWgt[base + 0] = s0;
                sWgt[base + 1] = s1;
                sWgt[base + 2] = s2;
                sWgt[base + 3] = s3;
            }
        }
    }
    __syncthreads();

    {
        const float score = (tid < T) ? (sWgt[tid] + b2v) : -1e30f;
        float m = score;
        #pragma unroll
        for (int off = 32; off > 0; off >>= 1) m = fmaxf(m, __shfl_xor(m, off));
        if (lane == 0) sRed[wid] = m;
        __syncthreads();
        const float gmax = fmaxf(fmaxf(sRed[0], sRed[1]), fmaxf(sRed[2], sRed[3]));
        const float p = (tid < T) ? __expf(score - gmax) : 0.f;
        float s = p;
        #pragma unroll
        for (int off = 32; off > 0; off >>= 1) s += __shfl_xor(s, off);
        if (lane == 0) sRed[4 + wid] = s;
        __syncthreads();
        const float gsum = sRed[4] + sRed[5] + sRed[6] + sRed[7];
        sWgt[tid] = p / gsum;
    }
    __syncthreads();

    {
        const int e = tid & 63, ch = tid >> 6;
        float a = 0.f;
        #pragma unroll 8
        for (int tt = 0; tt < 64; ++tt) {
            const int t = ch * 64 + tt;
            a = fmaf(sWgt[t], (float)sK[t * ROW + e], a);
        }
        sUP[tid] = a;
    }
    __syncthreads();
    if (tid < 64) sInt[tid] = sUP[tid] + sUP[64 + tid] + sUP[128 + tid] + sUP[192 + tid];
    __syncthreads();

    if (tid < 128) {
        float a = db1[tid];
        #pragma unroll 8
        for (int e = 0; e < 64; ++e) a = fmaf(sInt[e], dw1[e * 128 + tid], a);
        sD1[tid] = fmaxf(a, 0.f);
    }
    __syncthreads();
    if (tid < 64) {
        float a = db2[tid];
        #pragma unroll 8
        for (int i = 0; i < 128; ++i) a = fmaf(sD1[i], dw2[i * 64 + tid], a);
        sD2[tid] = fmaxf(a, 0.f);
    }
    __syncthreads();
    if (tid < 64) {
        float v = sD2[tid] * ow[tid];
        #pragma unroll
        for (int off = 32; off > 0; off >>= 1) v += __shfl_xor(v, off);
        if (tid == 0) out[b] = 1.f / (1.f + __expf(-(v + ob[0])));
    }
}

extern "C" void kernel_launch(void* const* d_in, const int* in_sizes, int n_in,
                              void* d_out, int out_size, void* d_ws, size_t ws_size,
                              hipStream_t stream) {
    const int*   query = (const int*)d_in[0];
    const int*   keys  = (const int*)d_in[1];
    const float* embf  = (const float*)d_in[2];
    const float* w1    = (const float*)d_in[3];
    const float* b1    = (const float*)d_in[4];
    const float* w2    = (const float*)d_in[5];
    const float* b2    = (const float*)d_in[6];
    const float* dw1   = (const float*)d_in[7];
    const float* db1   = (const float*)d_in[8];
    const float* dw2   = (const float*)d_in[9];
    const float* db2   = (const float*)d_in[10];
    const float* ow    = (const float*)d_in[11];
    const float* ob    = (const float*)d_in[12];
    float* out = (float*)d_out;
    const int B        = in_sizes[0];
    const int embElems = in_sizes[2];                  // VOCAB * E
    const size_t WOFF  = 49152;                        // Ap 16K | Ctf 16K | Dtf 16K

    if (ws_size >= WOFF + (size_t)embElems * 2) {
        float*  Ap    = (float*)d_ws;
        float*  Ctf   = (float*)((char*)d_ws + 16384);
        float*  Dtf   = (float*)((char*)d_ws + 32768);
        bf16_t* emb16 = (bf16_t*)((char*)d_ws + WOFF);
        const int n8 = embElems / 8;
        pre_cvt<<<16 + (n8 + 255) / 256, 256, 0, stream>>>(embf, emb16, n8,
                                                           w1, Ap, Ctf, Dtf);
        din_wave<<<B, 64, 0, stream>>>(query, keys, emb16, Ap, Ctf, Dtf,
                                       b1, w2, b2, dw1, db1, dw2, db2,
                                       ow, ob, out, B);
    } else {
        din_kernel<<<B, BDIM, 0, stream>>>(query, keys, embf, (const bf16_t*)d_ws, 0,
                                           w1, b1, w2, b2, dw1, db1, dw2, db2, ow, ob, out);
    }
}